// Round 8
// baseline (322.331 us; speedup 1.0000x reference)
//
#include <hip/hip_runtime.h>
#include <math.h>

// Sizes fixed by the reference: B=512, T=1024, D_IN=D_OUT=64, H=256.
#define HDIM 256
#define DDIM 64
#define BROWS 512
#define TSTEPS 1024
// Augmented rows: 65 weight rows (t-row + 64 state rows) + 1 bias row.
#define AROWS 66

typedef float f32x2 __attribute__((ext_vector_type(2)));

// ---- Setup: compose the linear MLP into one 66x64 affine map ----
__global__ void compose1(const float* __restrict__ W0, const float* __restrict__ b0,
                         const float* __restrict__ W1, const float* __restrict__ b1,
                         float* __restrict__ out1) {
    int r = blockIdx.x;    // 0..65
    int c = threadIdx.x;   // 0..255
    const float* arow = (r < 65) ? (W0 + r * HDIM) : b0;
    float acc = (r == 65) ? b1[c] : 0.0f;
    for (int h = 0; h < HDIM; ++h)
        acc = fmaf(arow[h], W1[h * HDIM + c], acc);
    out1[r * HDIM + c] = acc;
}

__global__ void compose2(const float* __restrict__ in1,
                         const float* __restrict__ W2, const float* __restrict__ b2,
                         float* __restrict__ out2) {
    int r = blockIdx.x, c = threadIdx.x;
    const float* arow = in1 + r * HDIM;
    float acc = (r == 65) ? b2[c] : 0.0f;
    for (int h = 0; h < HDIM; ++h)
        acc = fmaf(arow[h], W2[h * HDIM + c], acc);
    out2[r * HDIM + c] = acc;
}

__global__ void compose3(const float* __restrict__ in2,
                         const float* __restrict__ W3, const float* __restrict__ b3,
                         float* __restrict__ out3) {
    int r = blockIdx.x, c = threadIdx.x;   // c 0..63
    const float* arow = in2 + r * HDIM;
    float acc = (r == 65) ? b3[c] : 0.0f;
    for (int h = 0; h < HDIM; ++h)
        acc = fmaf(arow[h], W3[h * DDIM + c], acc);
    out3[r * DDIM + c] = acc;
}

// Packed 2xf32 FMA: acc.lo += a.lo*b.lo; acc.hi += a.hi*b.hi  (VOP3P, CDNA)
__device__ __forceinline__ void pkfma(f32x2& acc, f32x2 a, f32x2 b) {
    asm("v_pk_fma_f32 %0, %1, %2, %0" : "+v"(acc) : "v"(a), "v"(b));
}

// DPP controls
#define DPP_QP_XOR1 0xB1   // quad_perm [1,0,3,2]  -> lane ^ 1
#define DPP_QP_XOR2 0x4E   // quad_perm [2,3,0,1]  -> lane ^ 2
#define DPP_ROW_MIRROR 0x140      // lane ^ 15 (within row of 16)
#define DPP_ROW_HALF_MIRROR 0x141 // lane ^ 7  (within half-row of 8)

template <int CTRL>
__device__ __forceinline__ unsigned dpp_mov(unsigned v) {
    return (unsigned)__builtin_amdgcn_update_dpp(0, (int)v, CTRL, 0xF, 0xF, true);
}

// Butterfly all-gather stage tree (VALU-only; 2 swap stages + 3 DPP stages).
// Produces q[32]; the "odd partner" of q[c] is dpp_mov<DPP_QP_XOR1>(q[c]).
// The resulting per-lane source permutation is arbitrary-but-fixed; callers
// calibrate it by running this same network on the lane index as a probe.
__device__ __forceinline__ void gather32(unsigned v, unsigned q[32]) {
    unsigned t0, t1;
#if __has_builtin(__builtin_amdgcn_permlane32_swap)
    {
        auto s = __builtin_amdgcn_permlane32_swap((int)v, (int)v, false, false);
        t0 = (unsigned)s[0]; t1 = (unsigned)s[1];
    }
#else
    t0 = v;
    t1 = (unsigned)__builtin_amdgcn_ds_bpermute(
            (int)(((threadIdx.x ^ 32u) & 63u) << 2), (int)v);
#endif
    unsigned u[4];
#if __has_builtin(__builtin_amdgcn_permlane16_swap)
    {
        auto s = __builtin_amdgcn_permlane16_swap((int)t0, (int)t0, false, false);
        u[0] = (unsigned)s[0]; u[1] = (unsigned)s[1];
    }
    {
        auto s = __builtin_amdgcn_permlane16_swap((int)t1, (int)t1, false, false);
        u[2] = (unsigned)s[0]; u[3] = (unsigned)s[1];
    }
#else
    {
        int a16 = (int)(((threadIdx.x ^ 16u) & 63u) << 2);
        u[0] = t0; u[1] = (unsigned)__builtin_amdgcn_ds_bpermute(a16, (int)t0);
        u[2] = t1; u[3] = (unsigned)__builtin_amdgcn_ds_bpermute(a16, (int)t1);
    }
#endif
    unsigned w[8];
#pragma unroll
    for (int i = 0; i < 4; ++i) { w[i] = u[i]; w[4 + i] = dpp_mov<DPP_ROW_MIRROR>(u[i]); }
    unsigned xx[16];
#pragma unroll
    for (int i = 0; i < 8; ++i) { xx[i] = w[i]; xx[8 + i] = dpp_mov<DPP_ROW_HALF_MIRROR>(w[i]); }
#pragma unroll
    for (int i = 0; i < 16; ++i) { q[i] = xx[i]; q[16 + i] = dpp_mov<DPP_QP_XOR2>(xx[i]); }
}

// ---- Main scan: one wave per batch row, lane = output dim ----
// y_new[d] = y[d] + factor_k * tanh(b_eff[d] + t_k*w_t[d] + sum_j y[j]*Weff[j][d])
//
// The all-to-all y broadcast is a 63-op VALU butterfly (permlane_swap + DPP)
// — zero LDS/SGPR on the critical path, wide ILP. W is pre-permuted per
// lane to match the butterfly's (self-calibrated) source permutation.
__launch_bounds__(64, 1)
__global__ void fode_scan(const float* __restrict__ x, const float* __restrict__ t,
                          const float* __restrict__ Weff,   // 66 x 64 composed
                          float* __restrict__ out) {
    const int b = blockIdx.x;
    const int d = threadIdx.x;   // 0..63

    __shared__ float2 plds[TSTEPS];   // (t_k, factor_k); entry TSTEPS-1 unused

    const float invG = 0.56418958354775628695f;  // 1/Gamma(0.5)

    // Stage per-step params: coalesced, once per block (t is 4 KB, L2-hot).
    for (int i = d; i < TSTEPS - 1; i += DDIM) {
        float t0v = t[i];
        float t1v = t[i + 1];
        plds[i] = make_float2(t0v, sqrtf(t1v - t0v) * invG);
    }

    // Self-calibrate the gather network: probe with the lane index. After
    // this, sig[c] (resp. its xor1 partner) is the source lane of q[c]
    // (resp. partner) for ANY input, so Wp can be pre-permuted to match.
    unsigned sig[32];
    gather32((unsigned)d, sig);

    f32x2 Wp[32];
#pragma unroll
    for (int c = 0; c < 32; ++c) {
        unsigned j0 = sig[c];
        unsigned j1 = dpp_mov<DPP_QP_XOR1>(sig[c]);
        Wp[c].x = Weff[(1 + j0) * DDIM + d];
        Wp[c].y = Weff[(1 + j1) * DDIM + d];
    }
    const float wt   = Weff[d];                 // t-coefficient row
    const float bias = Weff[65 * DDIM + d];     // folded bias row

    float y = x[b * DDIM + d];
    float* op = out + (size_t)b * TSTEPS * DDIM + d;
    *op = y;                                     // solution[:,0,:] = x

    float2 prm = plds[0];                        // same-wave DS: in-order

    for (int k = 0; k < TSTEPS - 1; ++k) {
        float2 prm_next = plds[k + 1];           // prefetch; garbage at last iter, unused

        unsigned q[32];
        gather32(__float_as_uint(y), q);         // all-to-all, VALU only

        float base = fmaf(prm.x, wt, bias);      // t-term + bias
        f32x2 acc0 = {base, 0.f};
        f32x2 acc1 = {0.f, 0.f};
        f32x2 acc2 = {0.f, 0.f};
        f32x2 acc3 = {0.f, 0.f};
#pragma unroll
        for (int c = 0; c < 32; c += 4) {
            f32x2 p0, p1, p2, p3;
            p0.x = __uint_as_float(q[c + 0]);
            p0.y = __uint_as_float(dpp_mov<DPP_QP_XOR1>(q[c + 0]));
            p1.x = __uint_as_float(q[c + 1]);
            p1.y = __uint_as_float(dpp_mov<DPP_QP_XOR1>(q[c + 1]));
            p2.x = __uint_as_float(q[c + 2]);
            p2.y = __uint_as_float(dpp_mov<DPP_QP_XOR1>(q[c + 2]));
            p3.x = __uint_as_float(q[c + 3]);
            p3.y = __uint_as_float(dpp_mov<DPP_QP_XOR1>(q[c + 3]));
            pkfma(acc0, p0, Wp[c + 0]);
            pkfma(acc1, p1, Wp[c + 1]);
            pkfma(acc2, p2, Wp[c + 2]);
            pkfma(acc3, p3, Wp[c + 3]);
        }
        f32x2 accA = acc0 + acc1;                // v_pk_add_f32
        f32x2 accB = acc2 + acc3;
        f32x2 accT = accA + accB;
        float s = accT.x + accT.y;

        // tanh(s) = 1 - 2/(exp(2s)+1), via raw v_exp_f32 + v_rcp_f32
        float e  = __builtin_amdgcn_exp2f(s * 2.88539008177792681472f); // 2*log2(e)
        float th = fmaf(-2.0f, __builtin_amdgcn_rcpf(e + 1.0f), 1.0f);

        y = fmaf(prm.y, th, y);

        op += DDIM;
        *op = y;                                  // fire-and-forget, never waited
        prm = prm_next;
    }
}

extern "C" void kernel_launch(void* const* d_in, const int* in_sizes, int n_in,
                              void* d_out, int out_size, void* d_ws, size_t ws_size,
                              hipStream_t stream) {
    const float* x  = (const float*)d_in[0];
    const float* t  = (const float*)d_in[1];
    const float* W0 = (const float*)d_in[2];
    const float* b0 = (const float*)d_in[3];
    const float* W1 = (const float*)d_in[4];
    const float* b1 = (const float*)d_in[5];
    const float* W2 = (const float*)d_in[6];
    const float* b2 = (const float*)d_in[7];
    const float* W3 = (const float*)d_in[8];
    const float* b3 = (const float*)d_in[9];
    float* out = (float*)d_out;

    float* buf1 = (float*)d_ws;            // 66*256 floats
    float* buf2 = buf1 + AROWS * HDIM;     // 66*256 floats
    float* buf3 = buf2 + AROWS * HDIM;     // 66*64 floats

    compose1<<<AROWS, HDIM, 0, stream>>>(W0, b0, W1, b1, buf1);
    compose2<<<AROWS, HDIM, 0, stream>>>(buf1, W2, b2, buf2);
    compose3<<<AROWS, DDIM, 0, stream>>>(buf2, W3, b3, buf3);
    fode_scan<<<BROWS, DDIM, 0, stream>>>(x, t, buf3, out);
}

// Round 9
// 318.055 us; speedup vs baseline: 1.0134x; 1.0134x over previous
//
#include <hip/hip_runtime.h>
#include <math.h>

// Sizes fixed by the reference: B=512, T=1024, D_IN=D_OUT=64, H=256.
#define HDIM 256
#define DDIM 64
#define BROWS 512
#define TSTEPS 1024
// Augmented rows: 65 weight rows (t-row + 64 state rows) + 1 bias row.
#define AROWS 66

typedef float f32x2 __attribute__((ext_vector_type(2)));
typedef float f32x4 __attribute__((ext_vector_type(4)));

// ---- Setup: compose the linear MLP into one 66x64 affine map ----
__global__ void compose1(const float* __restrict__ W0, const float* __restrict__ b0,
                         const float* __restrict__ W1, const float* __restrict__ b1,
                         float* __restrict__ out1) {
    int r = blockIdx.x;    // 0..65
    int c = threadIdx.x;   // 0..255
    const float* arow = (r < 65) ? (W0 + r * HDIM) : b0;
    float acc = (r == 65) ? b1[c] : 0.0f;
    for (int h = 0; h < HDIM; ++h)
        acc = fmaf(arow[h], W1[h * HDIM + c], acc);
    out1[r * HDIM + c] = acc;
}

__global__ void compose2(const float* __restrict__ in1,
                         const float* __restrict__ W2, const float* __restrict__ b2,
                         float* __restrict__ out2) {
    int r = blockIdx.x, c = threadIdx.x;
    const float* arow = in1 + r * HDIM;
    float acc = (r == 65) ? b2[c] : 0.0f;
    for (int h = 0; h < HDIM; ++h)
        acc = fmaf(arow[h], W2[h * HDIM + c], acc);
    out2[r * HDIM + c] = acc;
}

__global__ void compose3(const float* __restrict__ in2,
                         const float* __restrict__ W3, const float* __restrict__ b3,
                         float* __restrict__ out3) {
    int r = blockIdx.x, c = threadIdx.x;   // c 0..63
    const float* arow = in2 + r * HDIM;
    float acc = (r == 65) ? b3[c] : 0.0f;
    for (int h = 0; h < HDIM; ++h)
        acc = fmaf(arow[h], W3[h * DDIM + c], acc);
    out3[r * DDIM + c] = acc;
}

// Packed 2xf32 FMA: acc.lo += a.lo*b.lo; acc.hi += a.hi*b.hi  (VOP3P, CDNA)
__device__ __forceinline__ void pkfma(f32x2& acc, f32x2 a, f32x2 b) {
    asm("v_pk_fma_f32 %0, %1, %2, %0" : "+v"(acc) : "v"(a), "v"(b));
}

// DPP controls (all verified correct by r8's self-calibrated pass)
#define DPP_QP_XOR1 0xB1          // quad_perm [1,0,3,2]  -> lane ^ 1
#define DPP_QP_XOR2 0x4E          // quad_perm [2,3,0,1]  -> lane ^ 2
#define DPP_ROW_MIRROR 0x140      // lane ^ 15 (within row of 16)
#define DPP_ROW_HALF_MIRROR 0x141 // lane ^ 7  (within half-row of 8)

template <int CTRL>
__device__ __forceinline__ unsigned dpp_mov(unsigned v) {
    return (unsigned)__builtin_amdgcn_update_dpp(0, (int)v, CTRL, 0xF, 0xF, true);
}

// Half-gather network: from per-lane value v, produce 32 regs q[0..31]
// containing v's values from one ALIGNED 32-half of the wave (which half
// is a fixed per-lane property of the swap semantics; callers calibrate
// by probing with the lane index). Structure:
//   permlane32_swap(v,v) -> A             (1 instr; one cross-half image)
//   permlane16_swap(A,A) -> q0,q1         (1 instr; together = {A, A^16})
//   xor1 / xor2 / xor7 / xor15 DPP tree   (30 movs)
// Masks {1,2,7,15} xor-span all of 0..15, so q covers the full 32-half.
__device__ __forceinline__ void gather_half(unsigned v, unsigned q[32]) {
    unsigned A;
    {
        auto s = __builtin_amdgcn_permlane32_swap((int)v, (int)v, false, false);
        A = (unsigned)s[0];
    }
    {
        auto s = __builtin_amdgcn_permlane16_swap((int)A, (int)A, false, false);
        q[0] = (unsigned)s[0];
        q[1] = (unsigned)s[1];
    }
    q[2] = dpp_mov<DPP_QP_XOR1>(q[0]);
    q[3] = dpp_mov<DPP_QP_XOR1>(q[1]);
#pragma unroll
    for (int i = 0; i < 4; ++i)  q[4 + i]  = dpp_mov<DPP_QP_XOR2>(q[i]);
#pragma unroll
    for (int i = 0; i < 8; ++i)  q[8 + i]  = dpp_mov<DPP_ROW_HALF_MIRROR>(q[i]);
#pragma unroll
    for (int i = 0; i < 16; ++i) q[16 + i] = dpp_mov<DPP_ROW_MIRROR>(q[i]);
}

// ---- Main scan: one wave per batch row, lane = output dim ----
// y_new[d] = y[d] + factor_k * tanh(b_eff[d] + t_k*w_t[d] + sum_j y[j]*Weff[j][d])
//
// Hybrid gather, both pipes in parallel:
//  - VALU half (32 j's): in-register butterfly on y (32 instrs), starts the
//    instant y exists — covers the LDS write->read turnaround. W coefficients
//    pre-permuted per lane via self-calibration (probe network with lane id).
//  - DS half (complement 32 j's): 8 ds_read_b128 issued at loop top
//    (issue-cheap: 0.25 instr/value); latency hides under the butterfly and
//    its 32 fmacs; consumed by 16 v_pk_fma_f32.
//  - complement base derived from the probe (robust to swap semantics).
// Loop has no global loads; one fire-and-forget store; compiler-only fence.
__launch_bounds__(64, 1)
__global__ void fode_scan(const float* __restrict__ x, const float* __restrict__ t,
                          const float* __restrict__ Weff,   // 66 x 64 composed
                          float* __restrict__ out) {
    const int b = blockIdx.x;
    const int d = threadIdx.x;   // 0..63

    __shared__ float  ylds[DDIM];
    __shared__ float2 plds[TSTEPS];   // (t_k, factor_k); entry TSTEPS-1 unused

    const float invG = 0.56418958354775628695f;  // 1/Gamma(0.5)

    // Stage per-step params: coalesced, once per block (t is 4 KB, L2-hot).
    for (int i = d; i < TSTEPS - 1; i += DDIM) {
        float t0 = t[i];
        float t1 = t[i + 1];
        plds[i] = make_float2(t0, sqrtf(t1 - t0) * invG);
    }

    // Self-calibrate: run the gather network on the lane index. sig[c] is
    // the source lane of q[c] for ANY input. All sig[] land in one aligned
    // 32-half (network masks are all <32 and the swaps preserve halves).
    unsigned sig[32];
    gather_half((unsigned)d, sig);

    float Wv[32];
#pragma unroll
    for (int c = 0; c < 32; ++c)
        Wv[c] = Weff[(1 + (int)sig[c]) * DDIM + d];

    // DS half covers the complement 32-half.
    const int dsj0 = (sig[0] < 32u) ? 32 : 0;
    f32x2 Wd[16];
#pragma unroll
    for (int c = 0; c < 16; ++c) {
        Wd[c].x = Weff[(1 + dsj0 + 2 * c + 0) * DDIM + d];
        Wd[c].y = Weff[(1 + dsj0 + 2 * c + 1) * DDIM + d];
    }
    const float wt   = Weff[d];                 // t-coefficient row
    const float bias = Weff[65 * DDIM + d];     // folded bias row

    float y = x[b * DDIM + d];
    float* op = out + (size_t)b * TSTEPS * DDIM + d;
    *op = y;                                     // solution[:,0,:] = x
    ylds[d] = y;
    asm volatile("" ::: "memory");               // write visible to loop reads

    float2 prm = plds[0];                        // same-wave DS: in-order

    for (int k = 0; k < TSTEPS - 1; ++k) {
        float2 prm_next = plds[k + 1];           // prefetch; garbage at last iter, unused

        // DS half: issue early; <=2 distinct addresses per read (conflict-free).
        f32x4 yv[8];
#pragma unroll
        for (int c = 0; c < 8; ++c)
            yv[c] = *reinterpret_cast<const f32x4*>(&ylds[dsj0 + 4 * c]);

        // VALU half: butterfly on the live y register (no memory).
        unsigned q[32];
        gather_half(__float_as_uint(y), q);

        float a0 = fmaf(prm.x, wt, bias), a1 = 0.f, a2 = 0.f, a3 = 0.f;
#pragma unroll
        for (int c = 0; c < 32; c += 4) {
            a0 = fmaf(__uint_as_float(q[c + 0]), Wv[c + 0], a0);
            a1 = fmaf(__uint_as_float(q[c + 1]), Wv[c + 1], a1);
            a2 = fmaf(__uint_as_float(q[c + 2]), Wv[c + 2], a2);
            a3 = fmaf(__uint_as_float(q[c + 3]), Wv[c + 3], a3);
        }

        // DS half consumption (reads have returned under the VALU work).
        f32x2 dacc0 = {0.f, 0.f}, dacc1 = {0.f, 0.f};
#pragma unroll
        for (int c = 0; c < 8; ++c) {
            f32x2 lo = __builtin_shufflevector(yv[c], yv[c], 0, 1);
            f32x2 hi = __builtin_shufflevector(yv[c], yv[c], 2, 3);
            pkfma(dacc0, lo, Wd[2 * c + 0]);
            pkfma(dacc1, hi, Wd[2 * c + 1]);
        }
        f32x2 dd = dacc0 + dacc1;                // v_pk_add_f32
        float s = ((a0 + a1) + (a2 + a3)) + (dd.x + dd.y);

        // tanh(s) = 1 - 2/(exp(2s)+1), via raw v_exp_f32 + v_rcp_f32
        float e  = __builtin_amdgcn_exp2f(s * 2.88539008177792681472f); // 2*log2(e)
        float th = fmaf(-2.0f, __builtin_amdgcn_rcpf(e + 1.0f), 1.0f);

        y = fmaf(prm.y, th, y);

        ylds[d] = y;                              // next iter's DS input (in-order)
        asm volatile("" ::: "memory");            // fence before next iter's reads
        op += DDIM;
        *op = y;                                  // fire-and-forget, never waited
        prm = prm_next;
    }
}

extern "C" void kernel_launch(void* const* d_in, const int* in_sizes, int n_in,
                              void* d_out, int out_size, void* d_ws, size_t ws_size,
                              hipStream_t stream) {
    const float* x  = (const float*)d_in[0];
    const float* t  = (const float*)d_in[1];
    const float* W0 = (const float*)d_in[2];
    const float* b0 = (const float*)d_in[3];
    const float* W1 = (const float*)d_in[4];
    const float* b1 = (const float*)d_in[5];
    const float* W2 = (const float*)d_in[6];
    const float* b2 = (const float*)d_in[7];
    const float* W3 = (const float*)d_in[8];
    const float* b3 = (const float*)d_in[9];
    float* out = (float*)d_out;

    float* buf1 = (float*)d_ws;            // 66*256 floats
    float* buf2 = buf1 + AROWS * HDIM;     // 66*256 floats
    float* buf3 = buf2 + AROWS * HDIM;     // 66*64 floats

    compose1<<<AROWS, HDIM, 0, stream>>>(W0, b0, W1, b1, buf1);
    compose2<<<AROWS, HDIM, 0, stream>>>(buf1, W2, b2, buf2);
    compose3<<<AROWS, DDIM, 0, stream>>>(buf2, W3, b3, buf3);
    fode_scan<<<BROWS, DDIM, 0, stream>>>(x, t, buf3, out);
}

// Round 10
// 318.004 us; speedup vs baseline: 1.0136x; 1.0002x over previous
//
#include <hip/hip_runtime.h>
#include <math.h>

// Sizes fixed by the reference: B=512, T=1024, D_IN=D_OUT=64, H=256.
#define HDIM 256
#define DDIM 64
#define BROWS 512
#define TSTEPS 1024
// Augmented rows: 65 weight rows (t-row + 64 state rows) + 1 bias row.
#define AROWS 66

typedef float f32x2 __attribute__((ext_vector_type(2)));
typedef float f32x4 __attribute__((ext_vector_type(4)));

// ---- Setup: compose the linear MLP into one 66x64 affine map ----
__global__ void compose1(const float* __restrict__ W0, const float* __restrict__ b0,
                         const float* __restrict__ W1, const float* __restrict__ b1,
                         float* __restrict__ out1) {
    int r = blockIdx.x;    // 0..65
    int c = threadIdx.x;   // 0..255
    const float* arow = (r < 65) ? (W0 + r * HDIM) : b0;
    float acc = (r == 65) ? b1[c] : 0.0f;
    for (int h = 0; h < HDIM; ++h)
        acc = fmaf(arow[h], W1[h * HDIM + c], acc);
    out1[r * HDIM + c] = acc;
}

__global__ void compose2(const float* __restrict__ in1,
                         const float* __restrict__ W2, const float* __restrict__ b2,
                         float* __restrict__ out2) {
    int r = blockIdx.x, c = threadIdx.x;
    const float* arow = in1 + r * HDIM;
    float acc = (r == 65) ? b2[c] : 0.0f;
    for (int h = 0; h < HDIM; ++h)
        acc = fmaf(arow[h], W2[h * HDIM + c], acc);
    out2[r * HDIM + c] = acc;
}

__global__ void compose3(const float* __restrict__ in2,
                         const float* __restrict__ W3, const float* __restrict__ b3,
                         float* __restrict__ out3) {
    int r = blockIdx.x, c = threadIdx.x;   // c 0..63
    const float* arow = in2 + r * HDIM;
    float acc = (r == 65) ? b3[c] : 0.0f;
    for (int h = 0; h < HDIM; ++h)
        acc = fmaf(arow[h], W3[h * DDIM + c], acc);
    out3[r * DDIM + c] = acc;
}

// Packed 2xf32 FMA: acc.lo += a.lo*b.lo; acc.hi += a.hi*b.hi  (VOP3P, CDNA)
__device__ __forceinline__ void pkfma(f32x2& acc, f32x2 a, f32x2 b) {
    asm("v_pk_fma_f32 %0, %1, %2, %0" : "+v"(acc) : "v"(a), "v"(b));
}

// DPP controls (all verified correct by r8's self-calibrated pass)
#define DPP_QP_XOR1 0xB1          // quad_perm [1,0,3,2]  -> lane ^ 1
#define DPP_QP_XOR2 0x4E          // quad_perm [2,3,0,1]  -> lane ^ 2
#define DPP_ROW_MIRROR 0x140      // lane ^ 15 (within row of 16)
#define DPP_ROW_HALF_MIRROR 0x141 // lane ^ 7  (within half-row of 8)

template <int CTRL>
__device__ __forceinline__ unsigned dpp_mov(unsigned v) {
    return (unsigned)__builtin_amdgcn_update_dpp(0, (int)v, CTRL, 0xF, 0xF, true);
}

// Half-gather network: from per-lane value v, produce 32 regs q[0..31]
// containing v's values from one ALIGNED 32-half of the wave (which half
// is a fixed per-lane property of the swap semantics; callers calibrate
// by probing with the lane index). Structure:
//   permlane32_swap(v,v) -> A             (1 instr; one cross-half image)
//   permlane16_swap(A,A) -> q0,q1         (1 instr; together = {A, A^16})
//   xor1 / xor2 / xor7 / xor15 DPP tree   (30 movs)
// Masks {1,2,7,15} xor-span all of 0..15, so q covers the full 32-half.
__device__ __forceinline__ void gather_half(unsigned v, unsigned q[32]) {
    unsigned A;
    {
        auto s = __builtin_amdgcn_permlane32_swap((int)v, (int)v, false, false);
        A = (unsigned)s[0];
    }
    {
        auto s = __builtin_amdgcn_permlane16_swap((int)A, (int)A, false, false);
        q[0] = (unsigned)s[0];
        q[1] = (unsigned)s[1];
    }
    q[2] = dpp_mov<DPP_QP_XOR1>(q[0]);
    q[3] = dpp_mov<DPP_QP_XOR1>(q[1]);
#pragma unroll
    for (int i = 0; i < 4; ++i)  q[4 + i]  = dpp_mov<DPP_QP_XOR2>(q[i]);
#pragma unroll
    for (int i = 0; i < 8; ++i)  q[8 + i]  = dpp_mov<DPP_ROW_HALF_MIRROR>(q[i]);
#pragma unroll
    for (int i = 0; i < 16; ++i) q[16 + i] = dpp_mov<DPP_ROW_MIRROR>(q[i]);
}

// ---- Main scan: one wave per batch row, lane = output dim ----
// y_new[d] = y[d] + factor_k * tanh(b_eff[d] + t_k*w_t[d] + sum_j y[j]*Weff[j][d])
//
// Hybrid gather, both pipes in parallel:
//  - VALU half (32 j's): in-register butterfly on y (32 instrs), starts the
//    instant y exists — covers the LDS write->read turnaround. W coefficients
//    pre-permuted per lane via self-calibration (probe network with lane id).
//  - DS half (complement 32 j's): 8 ds_read_b128 issued at loop top
//    (issue-cheap: 0.25 instr/value); latency hides under the butterfly and
//    its 32 fmacs; consumed by 16 v_pk_fma_f32.
//  - complement base derived from the probe (robust to swap semantics).
// Loop has no global loads; one fire-and-forget store; compiler-only fence.
__launch_bounds__(64, 1)
__global__ void fode_scan(const float* __restrict__ x, const float* __restrict__ t,
                          const float* __restrict__ Weff,   // 66 x 64 composed
                          float* __restrict__ out) {
    const int b = blockIdx.x;
    const int d = threadIdx.x;   // 0..63

    __shared__ float  ylds[DDIM];
    __shared__ float2 plds[TSTEPS];   // (t_k, factor_k); entry TSTEPS-1 unused

    const float invG = 0.56418958354775628695f;  // 1/Gamma(0.5)

    // Stage per-step params: coalesced, once per block (t is 4 KB, L2-hot).
    for (int i = d; i < TSTEPS - 1; i += DDIM) {
        float t0 = t[i];
        float t1 = t[i + 1];
        plds[i] = make_float2(t0, sqrtf(t1 - t0) * invG);
    }

    // Self-calibrate: run the gather network on the lane index. sig[c] is
    // the source lane of q[c] for ANY input. All sig[] land in one aligned
    // 32-half (network masks are all <32 and the swaps preserve halves).
    unsigned sig[32];
    gather_half((unsigned)d, sig);

    float Wv[32];
#pragma unroll
    for (int c = 0; c < 32; ++c)
        Wv[c] = Weff[(1 + (int)sig[c]) * DDIM + d];

    // DS half covers the complement 32-half.
    const int dsj0 = (sig[0] < 32u) ? 32 : 0;
    f32x2 Wd[16];
#pragma unroll
    for (int c = 0; c < 16; ++c) {
        Wd[c].x = Weff[(1 + dsj0 + 2 * c + 0) * DDIM + d];
        Wd[c].y = Weff[(1 + dsj0 + 2 * c + 1) * DDIM + d];
    }
    const float wt   = Weff[d];                 // t-coefficient row
    const float bias = Weff[65 * DDIM + d];     // folded bias row

    float y = x[b * DDIM + d];
    float* op = out + (size_t)b * TSTEPS * DDIM + d;
    *op = y;                                     // solution[:,0,:] = x
    ylds[d] = y;
    asm volatile("" ::: "memory");               // write visible to loop reads

    float2 prm = plds[0];                        // same-wave DS: in-order

    for (int k = 0; k < TSTEPS - 1; ++k) {
        float2 prm_next = plds[k + 1];           // prefetch; garbage at last iter, unused

        // DS half: issue early; <=2 distinct addresses per read (conflict-free).
        f32x4 yv[8];
#pragma unroll
        for (int c = 0; c < 8; ++c)
            yv[c] = *reinterpret_cast<const f32x4*>(&ylds[dsj0 + 4 * c]);

        // VALU half: butterfly on the live y register (no memory).
        unsigned q[32];
        gather_half(__float_as_uint(y), q);

        float a0 = fmaf(prm.x, wt, bias), a1 = 0.f, a2 = 0.f, a3 = 0.f;
#pragma unroll
        for (int c = 0; c < 32; c += 4) {
            a0 = fmaf(__uint_as_float(q[c + 0]), Wv[c + 0], a0);
            a1 = fmaf(__uint_as_float(q[c + 1]), Wv[c + 1], a1);
            a2 = fmaf(__uint_as_float(q[c + 2]), Wv[c + 2], a2);
            a3 = fmaf(__uint_as_float(q[c + 3]), Wv[c + 3], a3);
        }

        // DS half consumption (reads have returned under the VALU work).
        f32x2 dacc0 = {0.f, 0.f}, dacc1 = {0.f, 0.f};
#pragma unroll
        for (int c = 0; c < 8; ++c) {
            f32x2 lo = __builtin_shufflevector(yv[c], yv[c], 0, 1);
            f32x2 hi = __builtin_shufflevector(yv[c], yv[c], 2, 3);
            pkfma(dacc0, lo, Wd[2 * c + 0]);
            pkfma(dacc1, hi, Wd[2 * c + 1]);
        }
        f32x2 dd = dacc0 + dacc1;                // v_pk_add_f32
        float s = ((a0 + a1) + (a2 + a3)) + (dd.x + dd.y);

        // tanh(s) = 1 - 2/(exp(2s)+1), via raw v_exp_f32 + v_rcp_f32
        float e  = __builtin_amdgcn_exp2f(s * 2.88539008177792681472f); // 2*log2(e)
        float th = fmaf(-2.0f, __builtin_amdgcn_rcpf(e + 1.0f), 1.0f);

        y = fmaf(prm.y, th, y);

        ylds[d] = y;                              // next iter's DS input (in-order)
        asm volatile("" ::: "memory");            // fence before next iter's reads
        op += DDIM;
        *op = y;                                  // fire-and-forget, never waited
        prm = prm_next;
    }
}

extern "C" void kernel_launch(void* const* d_in, const int* in_sizes, int n_in,
                              void* d_out, int out_size, void* d_ws, size_t ws_size,
                              hipStream_t stream) {
    const float* x  = (const float*)d_in[0];
    const float* t  = (const float*)d_in[1];
    const float* W0 = (const float*)d_in[2];
    const float* b0 = (const float*)d_in[3];
    const float* W1 = (const float*)d_in[4];
    const float* b1 = (const float*)d_in[5];
    const float* W2 = (const float*)d_in[6];
    const float* b2 = (const float*)d_in[7];
    const float* W3 = (const float*)d_in[8];
    const float* b3 = (const float*)d_in[9];
    float* out = (float*)d_out;

    float* buf1 = (float*)d_ws;            // 66*256 floats
    float* buf2 = buf1 + AROWS * HDIM;     // 66*256 floats
    float* buf3 = buf2 + AROWS * HDIM;     // 66*64 floats

    compose1<<<AROWS, HDIM, 0, stream>>>(W0, b0, W1, b1, buf1);
    compose2<<<AROWS, HDIM, 0, stream>>>(buf1, W2, b2, buf2);
    compose3<<<AROWS, DDIM, 0, stream>>>(buf2, W3, b3, buf3);
    fode_scan<<<BROWS, DDIM, 0, stream>>>(x, t, buf3, out);
}